// Round 3
// baseline (333.735 us; speedup 1.0000x reference)
//
#include <hip/hip_runtime.h>
#include <hip/hip_fp16.h>

#define FDIM 128
#define NGRP 8   // XCD-partition groups (blockIdx & 7 round-robins XCDs)

typedef _Float16 half8_t __attribute__((ext_vector_type(8)));
typedef _Float16 half4_t __attribute__((ext_vector_type(4)));
typedef float float4_t __attribute__((ext_vector_type(4)));

// ---------------- CSR build ----------------

__global__ void zero_kernel(int* __restrict__ p, int n) {
  int i = blockIdx.x * blockDim.x + threadIdx.x;
  if (i < n) p[i] = 0;
}

// Replicated-read, partitioned-write histogram: group g = blockIdx&7 handles
// dst in [g*step, (g+1)*step) so deg lines stay single-XCD and writes merge in L2.
__global__ void hist_part_kernel(const int* __restrict__ dst, int* __restrict__ deg,
                                 int E, int step) {
  int grp = blockIdx.x & (NGRP - 1);
  int nb = gridDim.x >> 3, bid = blockIdx.x >> 3;
  int lo = grp * step, hi = lo + step;
  int E4 = E >> 2;
  const int4* d4 = (const int4*)dst;
  for (int i = bid * blockDim.x + threadIdx.x; i < E4; i += nb * blockDim.x) {
    int4 d = d4[i];
    if (d.x >= lo && d.x < hi) atomicAdd(&deg[d.x], 1);
    if (d.y >= lo && d.y < hi) atomicAdd(&deg[d.y], 1);
    if (d.z >= lo && d.z < hi) atomicAdd(&deg[d.z], 1);
    if (d.w >= lo && d.w < hi) atomicAdd(&deg[d.w], 1);
  }
  for (int e = (E4 << 2) + bid * blockDim.x + threadIdx.x; e < E; e += nb * blockDim.x) {
    int d = dst[e];
    if (d >= lo && d < hi) atomicAdd(&deg[d], 1);
  }
}

__global__ void scan1_kernel(const int* __restrict__ deg, int* __restrict__ csums, int N) {
  __shared__ int sh[256];
  int t = threadIdx.x, b = blockIdx.x;
  int base = b * 1024;
  int s = 0;
#pragma unroll
  for (int i = 0; i < 4; i++) {
    int idx = base + t + 256 * i;
    if (idx < N) s += deg[idx];
  }
  sh[t] = s; __syncthreads();
  for (int off = 128; off > 0; off >>= 1) {
    if (t < off) sh[t] += sh[t + off];
    __syncthreads();
  }
  if (t == 0) csums[b] = sh[0];
}

// one-block LDS exclusive scan over chunk sums (nchunk <= 256)
__global__ void scan2_kernel(const int* __restrict__ csums, int* __restrict__ coffs, int nchunk) {
  __shared__ int sh[256];
  int t = threadIdx.x;
  int v = (t < nchunk) ? csums[t] : 0;
  sh[t] = v; __syncthreads();
  for (int off = 1; off < 256; off <<= 1) {
    int u = (t >= off) ? sh[t - off] : 0;
    __syncthreads();
    sh[t] += u;
    __syncthreads();
  }
  if (t < nchunk) coffs[t] = sh[t] - v;
}

__global__ void scan3_kernel(const int* __restrict__ deg, const int* __restrict__ coffs,
                             int* __restrict__ row_start, int* __restrict__ fill_pos, int N) {
  __shared__ int sh[256];
  int t = threadIdx.x, b = blockIdx.x;
  int base = b * 1024 + t * 4;
  int d0 = (base + 0 < N) ? deg[base + 0] : 0;
  int d1 = (base + 1 < N) ? deg[base + 1] : 0;
  int d2 = (base + 2 < N) ? deg[base + 2] : 0;
  int d3 = (base + 3 < N) ? deg[base + 3] : 0;
  int l1 = d0, l2 = l1 + d1, l3 = l2 + d2, tot = l3 + d3;
  sh[t] = tot; __syncthreads();
  for (int off = 1; off < 256; off <<= 1) {
    int v = (t >= off) ? sh[t - off] : 0;
    __syncthreads();
    sh[t] += v;
    __syncthreads();
  }
  int excl = sh[t] - tot + coffs[b];
  if (base + 0 < N) { row_start[base + 0] = excl;      fill_pos[base + 0] = excl; }
  if (base + 1 < N) { row_start[base + 1] = excl + l1; fill_pos[base + 1] = excl + l1; }
  if (base + 2 < N) { row_start[base + 2] = excl + l2; fill_pos[base + 2] = excl + l2; }
  if (base + 3 < N) { row_start[base + 3] = excl + l3; fill_pos[base + 3] = excl + l3; }
}

// Replicated-read, partitioned-write placement: group g only places edges whose
// dst is in its node slice -> ssrc region per slice is written by one XCD group,
// lines fully merge in that L2 before writeback.
__global__ void place_part_kernel(const int* __restrict__ src, const int* __restrict__ dst,
                                  int* __restrict__ fill_pos, int* __restrict__ ssrc,
                                  int E, int step) {
  int grp = blockIdx.x & (NGRP - 1);
  int nb = gridDim.x >> 3, bid = blockIdx.x >> 3;
  int lo = grp * step, hi = lo + step;
  int E4 = E >> 2;
  const int4* d4 = (const int4*)dst;
  const int4* s4 = (const int4*)src;
  for (int i = bid * blockDim.x + threadIdx.x; i < E4; i += nb * blockDim.x) {
    int4 d = d4[i];
    int4 s = s4[i];
    if (d.x >= lo && d.x < hi) ssrc[atomicAdd(&fill_pos[d.x], 1)] = s.x;
    if (d.y >= lo && d.y < hi) ssrc[atomicAdd(&fill_pos[d.y], 1)] = s.y;
    if (d.z >= lo && d.z < hi) ssrc[atomicAdd(&fill_pos[d.z], 1)] = s.z;
    if (d.w >= lo && d.w < hi) ssrc[atomicAdd(&fill_pos[d.w], 1)] = s.w;
  }
  for (int e = (E4 << 2) + bid * blockDim.x + threadIdx.x; e < E; e += nb * blockDim.x) {
    int d = dst[e];
    if (d >= lo && d < hi) ssrc[atomicAdd(&fill_pos[d], 1)] = src[e];
  }
}

// ---------------- convert fp32 -> fp16 ----------------

__global__ void cvt_f2h_kernel(const float* __restrict__ in, _Float16* __restrict__ out, int n4) {
  int i = blockIdx.x * blockDim.x + threadIdx.x;
  if (i < n4) {
    float4 v = ((const float4*)in)[i];
    half4_t h;
    h.x = (_Float16)v.x; h.y = (_Float16)v.y; h.z = (_Float16)v.z; h.w = (_Float16)v.w;
    ((half4_t*)out)[i] = h;
  }
}

// ---------------- aggregation (one wave per node, fp16 rows) ----------------

__device__ inline float2 up2(unsigned u) {
  __half2 h = *(__half2*)&u;
  return __half22float2(h);
}

__global__ void agg1_kernel(const unsigned* __restrict__ xu, const int* __restrict__ row_start,
                            const int* __restrict__ deg, const int* __restrict__ ssrc,
                            unsigned* __restrict__ outu, int N) {
  int wave = (blockIdx.x * blockDim.x + threadIdx.x) >> 6;
  int lane = threadIdx.x & 63;
  if (wave >= N) return;
  float2 acc = up2(xu[(size_t)wave * 64 + lane]);
  float2 accb = make_float2(0.f, 0.f);
  int start = row_start[wave], d = deg[wave];
  int k = 0;
  for (; k + 3 < d; k += 4) {
    int s0 = ssrc[start + k], s1 = ssrc[start + k + 1];
    int s2 = ssrc[start + k + 2], s3 = ssrc[start + k + 3];
    unsigned u0 = xu[(size_t)s0 * 64 + lane];
    unsigned u1 = xu[(size_t)s1 * 64 + lane];
    unsigned u2 = xu[(size_t)s2 * 64 + lane];
    unsigned u3 = xu[(size_t)s3 * 64 + lane];
    float2 v0 = up2(u0), v1 = up2(u1), v2 = up2(u2), v3 = up2(u3);
    acc.x += v0.x + v2.x; acc.y += v0.y + v2.y;
    accb.x += v1.x + v3.x; accb.y += v1.y + v3.y;
  }
  for (; k < d; k++) {
    float2 v = up2(xu[(size_t)ssrc[start + k] * 64 + lane]);
    acc.x += v.x; acc.y += v.y;
  }
  acc.x += accb.x; acc.y += accb.y;
  __half2 r = __float22half2_rn(acc);
  outu[(size_t)wave * 64 + lane] = *(unsigned*)&r;
}

__global__ void agg2_kernel(const unsigned* __restrict__ hu, const int* __restrict__ row_start,
                            const int* __restrict__ deg, const int* __restrict__ ssrc,
                            const float* __restrict__ a, const float* __restrict__ c,
                            unsigned* __restrict__ outu, int N) {
  int wave = (blockIdx.x * blockDim.x + threadIdx.x) >> 6;
  int lane = threadIdx.x & 63;
  if (wave >= N) return;
  float2 acc = up2(hu[(size_t)wave * 64 + lane]);
  float2 accb = make_float2(0.f, 0.f);
  int start = row_start[wave], d = deg[wave];
  int k = 0;
  for (; k + 3 < d; k += 4) {
    int s0 = ssrc[start + k], s1 = ssrc[start + k + 1];
    int s2 = ssrc[start + k + 2], s3 = ssrc[start + k + 3];
    unsigned u0 = hu[(size_t)s0 * 64 + lane];
    unsigned u1 = hu[(size_t)s1 * 64 + lane];
    unsigned u2 = hu[(size_t)s2 * 64 + lane];
    unsigned u3 = hu[(size_t)s3 * 64 + lane];
    float2 v0 = up2(u0), v1 = up2(u1), v2 = up2(u2), v3 = up2(u3);
    acc.x += v0.x + v2.x; acc.y += v0.y + v2.y;
    accb.x += v1.x + v3.x; accb.y += v1.y + v3.y;
  }
  for (; k < d; k++) {
    float2 v = up2(hu[(size_t)ssrc[start + k] * 64 + lane]);
    acc.x += v.x; acc.y += v.y;
  }
  acc.x += accb.x; acc.y += accb.y;
  float2 av = ((const float2*)a)[lane];
  float2 cv = ((const float2*)c)[lane];
  float dn = (float)(d + 1);
  float2 r;
  r.x = av.x * acc.x + dn * cv.x;
  r.y = av.y * acc.y + dn * cv.y;
  __half2 rh = __float22half2_rn(r);
  outu[(size_t)wave * 64 + lane] = *(unsigned*)&rh;
}

// ---------------- MFMA f16 GEMM: (N x 128) @ (128 x 128) + bias, ReLU ----------------

template <bool HALF_OUT>
__global__ __launch_bounds__(256) void gemm_mfma_kernel(
    const _Float16* __restrict__ in, const _Float16* __restrict__ W,
    const float* __restrict__ bias, void* __restrict__ out, int N) {
  int t = threadIdx.x;
  int wave = t >> 6, lane = t & 63;
  int quad = lane >> 4, m16 = lane & 15;
  int row0 = blockIdx.x * 16;
  int col0 = wave * 32;

  half8_t bfrag[2][4];
#pragma unroll
  for (int ct = 0; ct < 2; ct++)
#pragma unroll
    for (int kb = 0; kb < 4; kb++) {
      int col = col0 + ct * 16 + m16;
#pragma unroll
      for (int j = 0; j < 8; j++)
        bfrag[ct][kb][j] = W[(size_t)(kb * 32 + quad * 8 + j) * FDIM + col];
    }

  int arow = row0 + m16;
  if (arow >= N) arow = N - 1;

  float4_t acc0 = {0.f, 0.f, 0.f, 0.f};
  float4_t acc1 = {0.f, 0.f, 0.f, 0.f};
#pragma unroll
  for (int kb = 0; kb < 4; kb++) {
    half8_t a = *(const half8_t*)(in + (size_t)arow * FDIM + kb * 32 + quad * 8);
    acc0 = __builtin_amdgcn_mfma_f32_16x16x32_f16(a, bfrag[0][kb], acc0, 0, 0, 0);
    acc1 = __builtin_amdgcn_mfma_f32_16x16x32_f16(a, bfrag[1][kb], acc1, 0, 0, 0);
  }

#pragma unroll
  for (int ct = 0; ct < 2; ct++) {
    float4_t acc = ct ? acc1 : acc0;
    int col = col0 + ct * 16 + m16;
    float bv = bias[col];
#pragma unroll
    for (int r = 0; r < 4; r++) {
      int row = row0 + quad * 4 + r;
      if (row < N) {
        float v = fmaxf(acc[r] + bv, 0.f);
        if (HALF_OUT)
          ((_Float16*)out)[(size_t)row * FDIM + col] = (_Float16)v;
        else
          ((float*)out)[(size_t)row * FDIM + col] = v;
      }
    }
  }
}

// ---------------- BN stats (fp16 input) / coeffs / apply ----------------

__global__ void stats_h_kernel(const _Float16* __restrict__ h, float* __restrict__ sum,
                               float* __restrict__ sq, int N) {
  __shared__ float red[8 * FDIM];
  int t = threadIdx.x;
  int tx = t & 31, ty = t >> 5;
  int c0 = tx * 4;
  float4 s = make_float4(0.f, 0.f, 0.f, 0.f);
  float4 q = s;
  for (int r = blockIdx.x * 8 + ty; r < N; r += gridDim.x * 8) {
    const __half2* p = (const __half2*)&h[(size_t)r * FDIM + c0];
    float2 v0 = __half22float2(p[0]);
    float2 v1 = __half22float2(p[1]);
    s.x += v0.x; s.y += v0.y; s.z += v1.x; s.w += v1.y;
    q.x += v0.x * v0.x; q.y += v0.y * v0.y; q.z += v1.x * v1.x; q.w += v1.y * v1.y;
  }
  *(float4*)&red[ty * FDIM + c0] = s;
  __syncthreads();
  if (t < FDIM) {
    float tot = 0.f;
#pragma unroll
    for (int j = 0; j < 8; j++) tot += red[j * FDIM + t];
    atomicAdd(&sum[t], tot);
  }
  __syncthreads();
  *(float4*)&red[ty * FDIM + c0] = q;
  __syncthreads();
  if (t < FDIM) {
    float tot = 0.f;
#pragma unroll
    for (int j = 0; j < 8; j++) tot += red[j * FDIM + t];
    atomicAdd(&sq[t], tot);
  }
}

__global__ void coeffs_kernel(const float* __restrict__ sum, const float* __restrict__ sq,
                              const float* __restrict__ gamma, const float* __restrict__ beta,
                              float* __restrict__ a, float* __restrict__ c, int N) {
  int t = threadIdx.x;
  if (t < FDIM) {
    float invn = 1.f / (float)N;
    float mean = sum[t] * invn;
    float var = sq[t] * invn - mean * mean;
    float rs = rsqrtf(var + 1e-5f);
    float av = gamma[t] * rs;
    a[t] = av;
    c[t] = beta[t] - mean * av;
  }
}

// BN2: read fp16 h2, write fp32 out
__global__ void apply_h_kernel(const uint2* __restrict__ h4, const float* __restrict__ a,
                               const float* __restrict__ c, float4* __restrict__ out, int n4) {
  int i = blockIdx.x * blockDim.x + threadIdx.x;
  if (i < n4) {
    uint2 u = h4[i];
    float2 v0 = up2(u.x), v1 = up2(u.y);
    int c4 = i & 31;
    float4 av = ((const float4*)a)[c4];
    float4 cv = ((const float4*)c)[c4];
    float4 o;
    o.x = av.x * v0.x + cv.x;
    o.y = av.y * v0.y + cv.y;
    o.z = av.z * v1.x + cv.z;
    o.w = av.w * v1.y + cv.w;
    out[i] = o;
  }
}

// ---------------- launch ----------------

extern "C" void kernel_launch(void* const* d_in, const int* in_sizes, int n_in,
                              void* d_out, int out_size, void* d_ws, size_t ws_size,
                              hipStream_t stream) {
  const float* x   = (const float*)d_in[0];
  const int*   ei  = (const int*)d_in[1];
  const float* W1  = (const float*)d_in[2];
  const float* b1  = (const float*)d_in[3];
  const float* W2  = (const float*)d_in[4];
  const float* b2  = (const float*)d_in[5];
  const float* g1  = (const float*)d_in[6];
  const float* be1 = (const float*)d_in[7];
  const float* g2  = (const float*)d_in[8];
  const float* be2 = (const float*)d_in[9];
  float* out = (float*)d_out;

  const int N = in_sizes[0] / FDIM;
  const int E = in_sizes[1] / 2;
  const int* src = ei;
  const int* dst = ei + E;

  auto align256 = [](char*& q) { q = (char*)(((uintptr_t)q + 255) & ~(uintptr_t)255); };

  char* p = (char*)d_ws;
  int* deg = (int*)p;        p += (size_t)N * 4;
  float* stats = (float*)p;  p += 1024 * 4;
  align256(p);
  int* row_start = (int*)p;  p += (size_t)N * 4; align256(p);
  int* fill_pos = (int*)p;   p += (size_t)N * 4; align256(p);
  int* csums = (int*)p;      p += 256 * 4;
  int* coffs = (int*)p;      p += 256 * 4; align256(p);
  int* ssrc = (int*)p;       p += (size_t)E * 4; align256(p);
  _Float16* xh  = (_Float16*)p; p += (size_t)N * FDIM * 2; align256(p);
  _Float16* tmp = (_Float16*)p; p += (size_t)N * FDIM * 2; align256(p);
  _Float16* h1  = (_Float16*)p; p += (size_t)N * FDIM * 2; align256(p);
  _Float16* W1h = (_Float16*)p; p += FDIM * FDIM * 2;
  _Float16* W2h = (_Float16*)p; p += FDIM * FDIM * 2;

  float* s1 = stats + 0,   *q1 = stats + 128;
  float* s2 = stats + 256, *q2 = stats + 384;
  float* a1 = stats + 512, *c1 = stats + 640;
  float* a2 = stats + 768, *c2 = stats + 896;

  const int nchunk = (N + 1023) / 1024;
  const int ntiles = (N + 15) / 16;
  const int step = (N + NGRP - 1) / NGRP;

  // CSR build + conversions
  int zn = N + 1024;
  zero_kernel<<<(zn + 255) / 256, 256, 0, stream>>>(deg, zn);
  hist_part_kernel<<<NGRP * 96, 256, 0, stream>>>(dst, deg, E, step);
  cvt_f2h_kernel<<<(N * 32 + 255) / 256, 256, 0, stream>>>(x, xh, N * 32);
  cvt_f2h_kernel<<<(FDIM * 32 + 255) / 256, 256, 0, stream>>>(W1, W1h, FDIM * 32);
  cvt_f2h_kernel<<<(FDIM * 32 + 255) / 256, 256, 0, stream>>>(W2, W2h, FDIM * 32);
  scan1_kernel<<<nchunk, 256, 0, stream>>>(deg, csums, N);
  scan2_kernel<<<1, 256, 0, stream>>>(csums, coffs, nchunk);
  scan3_kernel<<<nchunk, 256, 0, stream>>>(deg, coffs, row_start, fill_pos, N);
  place_part_kernel<<<NGRP * 96, 256, 0, stream>>>(src, dst, fill_pos, ssrc, E, step);

  // layer 1
  agg1_kernel<<<(N + 3) / 4, 256, 0, stream>>>((const unsigned*)xh, row_start, deg, ssrc,
                                               (unsigned*)tmp, N);
  gemm_mfma_kernel<true><<<ntiles, 256, 0, stream>>>(tmp, W1h, b1, h1, N);
  stats_h_kernel<<<256, 256, 0, stream>>>(h1, s1, q1, N);
  coeffs_kernel<<<1, 128, 0, stream>>>(s1, q1, g1, be1, a1, c1, N);

  // layer 2 (BN1 folded into aggregation); gemm2 writes fp16 back into h1
  agg2_kernel<<<(N + 3) / 4, 256, 0, stream>>>((const unsigned*)h1, row_start, deg, ssrc,
                                               a1, c1, (unsigned*)tmp, N);
  gemm_mfma_kernel<true><<<ntiles, 256, 0, stream>>>(tmp, W2h, b2, h1, N);
  stats_h_kernel<<<256, 256, 0, stream>>>(h1, s2, q2, N);
  coeffs_kernel<<<1, 128, 0, stream>>>(s2, q2, g2, be2, a2, c2, N);

  // BN2: fp16 h2 -> fp32 out
  int n4 = N * 32;
  apply_h_kernel<<<(n4 + 255) / 256, 256, 0, stream>>>((const uint2*)h1, a2, c2,
                                                       (float4*)out, n4);
}

// Round 4
// 319.930 us; speedup vs baseline: 1.0432x; 1.0432x over previous
//
#include <hip/hip_runtime.h>
#include <hip/hip_fp16.h>

#define FDIM 128
#define NGRP 8   // XCD-partition groups (blockIdx & 7 round-robins XCDs)

typedef _Float16 half8_t __attribute__((ext_vector_type(8)));
typedef _Float16 half4_t __attribute__((ext_vector_type(4)));
typedef float float4_t __attribute__((ext_vector_type(4)));

// ---------------- CSR build ----------------

__global__ void zero_kernel(int* __restrict__ p, int n) {
  int i = blockIdx.x * blockDim.x + threadIdx.x;
  if (i < n) p[i] = 0;
}

// Replicated-read, partitioned-write histogram (dst slice per XCD group).
__global__ void hist_part_kernel(const int* __restrict__ dst, int* __restrict__ deg,
                                 int E, int step) {
  int grp = blockIdx.x & (NGRP - 1);
  int nb = gridDim.x >> 3, bid = blockIdx.x >> 3;
  int lo = grp * step, hi = lo + step;
  int E4 = E >> 2;
  const int4* d4 = (const int4*)dst;
  for (int i = bid * blockDim.x + threadIdx.x; i < E4; i += nb * blockDim.x) {
    int4 d = d4[i];
    if (d.x >= lo && d.x < hi) atomicAdd(&deg[d.x], 1);
    if (d.y >= lo && d.y < hi) atomicAdd(&deg[d.y], 1);
    if (d.z >= lo && d.z < hi) atomicAdd(&deg[d.z], 1);
    if (d.w >= lo && d.w < hi) atomicAdd(&deg[d.w], 1);
  }
  for (int e = (E4 << 2) + bid * blockDim.x + threadIdx.x; e < E; e += nb * blockDim.x) {
    int d = dst[e];
    if (d >= lo && d < hi) atomicAdd(&deg[d], 1);
  }
}

__global__ void scan1_kernel(const int* __restrict__ deg, int* __restrict__ csums, int N) {
  __shared__ int sh[256];
  int t = threadIdx.x, b = blockIdx.x;
  int base = b * 1024;
  int s = 0;
#pragma unroll
  for (int i = 0; i < 4; i++) {
    int idx = base + t + 256 * i;
    if (idx < N) s += deg[idx];
  }
  sh[t] = s; __syncthreads();
  for (int off = 128; off > 0; off >>= 1) {
    if (t < off) sh[t] += sh[t + off];
    __syncthreads();
  }
  if (t == 0) csums[b] = sh[0];
}

__global__ void scan2_kernel(const int* __restrict__ csums, int* __restrict__ coffs, int nchunk) {
  __shared__ int sh[256];
  int t = threadIdx.x;
  int v = (t < nchunk) ? csums[t] : 0;
  sh[t] = v; __syncthreads();
  for (int off = 1; off < 256; off <<= 1) {
    int u = (t >= off) ? sh[t - off] : 0;
    __syncthreads();
    sh[t] += u;
    __syncthreads();
  }
  if (t < nchunk) coffs[t] = sh[t] - v;
}

__global__ void scan3_kernel(const int* __restrict__ deg, const int* __restrict__ coffs,
                             int* __restrict__ row_start, int* __restrict__ fill_pos, int N) {
  __shared__ int sh[256];
  int t = threadIdx.x, b = blockIdx.x;
  int base = b * 1024 + t * 4;
  int d0 = (base + 0 < N) ? deg[base + 0] : 0;
  int d1 = (base + 1 < N) ? deg[base + 1] : 0;
  int d2 = (base + 2 < N) ? deg[base + 2] : 0;
  int d3 = (base + 3 < N) ? deg[base + 3] : 0;
  int l1 = d0, l2 = l1 + d1, l3 = l2 + d2, tot = l3 + d3;
  sh[t] = tot; __syncthreads();
  for (int off = 1; off < 256; off <<= 1) {
    int v = (t >= off) ? sh[t - off] : 0;
    __syncthreads();
    sh[t] += v;
    __syncthreads();
  }
  int excl = sh[t] - tot + coffs[b];
  if (base + 0 < N) { row_start[base + 0] = excl;      fill_pos[base + 0] = excl; }
  if (base + 1 < N) { row_start[base + 1] = excl + l1; fill_pos[base + 1] = excl + l1; }
  if (base + 2 < N) { row_start[base + 2] = excl + l2; fill_pos[base + 2] = excl + l2; }
  if (base + 3 < N) { row_start[base + 3] = excl + l3; fill_pos[base + 3] = excl + l3; }
}

__global__ void place_part_kernel(const int* __restrict__ src, const int* __restrict__ dst,
                                  int* __restrict__ fill_pos, int* __restrict__ ssrc,
                                  int E, int step) {
  int grp = blockIdx.x & (NGRP - 1);
  int nb = gridDim.x >> 3, bid = blockIdx.x >> 3;
  int lo = grp * step, hi = lo + step;
  int E4 = E >> 2;
  const int4* d4 = (const int4*)dst;
  const int4* s4 = (const int4*)src;
  for (int i = bid * blockDim.x + threadIdx.x; i < E4; i += nb * blockDim.x) {
    int4 d = d4[i];
    int4 s = s4[i];
    if (d.x >= lo && d.x < hi) ssrc[atomicAdd(&fill_pos[d.x], 1)] = s.x;
    if (d.y >= lo && d.y < hi) ssrc[atomicAdd(&fill_pos[d.y], 1)] = s.y;
    if (d.z >= lo && d.z < hi) ssrc[atomicAdd(&fill_pos[d.z], 1)] = s.z;
    if (d.w >= lo && d.w < hi) ssrc[atomicAdd(&fill_pos[d.w], 1)] = s.w;
  }
  for (int e = (E4 << 2) + bid * blockDim.x + threadIdx.x; e < E; e += nb * blockDim.x) {
    int d = dst[e];
    if (d >= lo && d < hi) ssrc[atomicAdd(&fill_pos[d], 1)] = src[e];
  }
}

// ---------------- convert / W pre-shuffle ----------------

__global__ void cvt_f2h_kernel(const float* __restrict__ in, _Float16* __restrict__ out, int n4) {
  int i = blockIdx.x * blockDim.x + threadIdx.x;
  if (i < n4) {
    float4 v = ((const float4*)in)[i];
    half4_t h;
    h.x = (_Float16)v.x; h.y = (_Float16)v.y; h.z = (_Float16)v.z; h.w = (_Float16)v.w;
    ((half4_t*)out)[i] = h;
  }
}

// Shuffle W (fp32 row-major [k][n]) into per-lane MFMA B-fragment order so the
// GEMM loads each fragment as one coalesced half8:
//   Wf[((wave*2+ct)*4+kb)*64 + lane][j] = W[(kb*32+quad*8+j)*128 + wave*32+ct*16+m16]
__global__ void prepw_kernel(const float* __restrict__ W, _Float16* __restrict__ Wf) {
  int tid = blockIdx.x * blockDim.x + threadIdx.x;  // 16384
  int j = tid & 7, lane = (tid >> 3) & 63, rest = tid >> 9;
  int kb = rest & 3, ct = (rest >> 2) & 1, wave = rest >> 3;
  int quad = lane >> 4, m16 = lane & 15;
  int k = kb * 32 + quad * 8 + j;
  int n = wave * 32 + ct * 16 + m16;
  Wf[tid] = (_Float16)W[k * FDIM + n];
}

// ---------------- aggregation (one wave per node, fp16 rows, unroll 8) ----------------

__device__ inline float2 up2(unsigned u) {
  __half2 h = *(__half2*)&u;
  return __half22float2(h);
}

template <bool SCALE>
__global__ void agg_kernel(const unsigned* __restrict__ xu, const int* __restrict__ row_start,
                           const int* __restrict__ deg, const int* __restrict__ ssrc,
                           const float* __restrict__ a, unsigned* __restrict__ outu, int N) {
  int wave = (blockIdx.x * blockDim.x + threadIdx.x) >> 6;
  int lane = threadIdx.x & 63;
  if (wave >= N) return;
  float2 c0 = up2(xu[(size_t)wave * 64 + lane]);
  float2 c1 = make_float2(0.f, 0.f), c2 = c1, c3 = c1;
  int start = row_start[wave], d = deg[wave];
  int k = 0;
  for (; k + 7 < d; k += 8) {
    int s0 = ssrc[start + k + 0], s1 = ssrc[start + k + 1];
    int s2 = ssrc[start + k + 2], s3 = ssrc[start + k + 3];
    int s4 = ssrc[start + k + 4], s5 = ssrc[start + k + 5];
    int s6 = ssrc[start + k + 6], s7 = ssrc[start + k + 7];
    unsigned u0 = xu[(size_t)s0 * 64 + lane], u1 = xu[(size_t)s1 * 64 + lane];
    unsigned u2 = xu[(size_t)s2 * 64 + lane], u3 = xu[(size_t)s3 * 64 + lane];
    unsigned u4 = xu[(size_t)s4 * 64 + lane], u5 = xu[(size_t)s5 * 64 + lane];
    unsigned u6 = xu[(size_t)s6 * 64 + lane], u7 = xu[(size_t)s7 * 64 + lane];
    float2 v0 = up2(u0), v1 = up2(u1), v2 = up2(u2), v3 = up2(u3);
    float2 v4 = up2(u4), v5 = up2(u5), v6 = up2(u6), v7 = up2(u7);
    c0.x += v0.x + v4.x; c0.y += v0.y + v4.y;
    c1.x += v1.x + v5.x; c1.y += v1.y + v5.y;
    c2.x += v2.x + v6.x; c2.y += v2.y + v6.y;
    c3.x += v3.x + v7.x; c3.y += v3.y + v7.y;
  }
  for (; k + 1 < d; k += 2) {
    int s0 = ssrc[start + k], s1 = ssrc[start + k + 1];
    unsigned u0 = xu[(size_t)s0 * 64 + lane], u1 = xu[(size_t)s1 * 64 + lane];
    float2 v0 = up2(u0), v1 = up2(u1);
    c0.x += v0.x; c0.y += v0.y;
    c1.x += v1.x; c1.y += v1.y;
  }
  if (k < d) {
    float2 v = up2(xu[(size_t)ssrc[start + k] * 64 + lane]);
    c0.x += v.x; c0.y += v.y;
  }
  float2 acc;
  acc.x = (c0.x + c1.x) + (c2.x + c3.x);
  acc.y = (c0.y + c1.y) + (c2.y + c3.y);
  if (SCALE) {
    float2 av = ((const float2*)a)[lane];
    acc.x *= av.x; acc.y *= av.y;
  }
  __half2 r = __float22half2_rn(acc);
  outu[(size_t)wave * 64 + lane] = *(unsigned*)&r;
}

// ---------------- MFMA GEMM: 64 rows/block, fused bias(+deg*r2), ReLU, stats ----------------
// C/D layout: row = quad*4 + reg, col = lane&15 (m89-verified).

template <bool LAYER2>
__global__ __launch_bounds__(256) void gemm_kernel(
    const _Float16* __restrict__ in, const _Float16* __restrict__ Wf,
    const float* __restrict__ bias, const float* __restrict__ r2,
    const int* __restrict__ deg, _Float16* __restrict__ outh,
    float* __restrict__ ssum, float* __restrict__ ssq, int N) {
  int t = threadIdx.x;
  int wave = t >> 6, lane = t & 63;
  int quad = lane >> 4, m16 = lane & 15;
  int row0 = blockIdx.x * 64;

  __shared__ float sdn[64];
  if (LAYER2) {
    if (t < 64) {
      int r = row0 + t;
      sdn[t] = (r < N) ? (float)(deg[r] + 1) : 0.f;
    }
    __syncthreads();
  }

  // B fragments: 8 coalesced half8 loads from pre-shuffled Wf (L2-hot, 32 KB)
  half8_t bf[2][4];
  const half8_t* wf8 = (const half8_t*)Wf;
#pragma unroll
  for (int ct = 0; ct < 2; ct++)
#pragma unroll
    for (int kb = 0; kb < 4; kb++)
      bf[ct][kb] = wf8[(size_t)(((wave * 2 + ct) * 4 + kb) * 64 + lane)];

  float4_t acc[4][2] = {};
#pragma unroll
  for (int rt = 0; rt < 4; rt++) {
    int arow = row0 + rt * 16 + m16;
    int cr = (arow < N) ? arow : N - 1;  // safe duplicate read; stores guarded
#pragma unroll
    for (int kb = 0; kb < 4; kb++) {
      half8_t av = *(const half8_t*)(in + (size_t)cr * FDIM + kb * 32 + quad * 8);
      acc[rt][0] = __builtin_amdgcn_mfma_f32_16x16x32_f16(av, bf[0][kb], acc[rt][0], 0, 0, 0);
      acc[rt][1] = __builtin_amdgcn_mfma_f32_16x16x32_f16(av, bf[1][kb], acc[rt][1], 0, 0, 0);
    }
  }

#pragma unroll
  for (int ct = 0; ct < 2; ct++) {
    int col = wave * 32 + ct * 16 + m16;
    float bv = bias[col];
    float rv = LAYER2 ? r2[col] : 0.f;
    float s = 0.f, q = 0.f;
#pragma unroll
    for (int rt = 0; rt < 4; rt++) {
#pragma unroll
      for (int r = 0; r < 4; r++) {
        int row = row0 + rt * 16 + quad * 4 + r;
        if (row < N) {
          float v = acc[rt][ct][r] + bv;
          if (LAYER2) v += sdn[rt * 16 + quad * 4 + r] * rv;
          v = fmaxf(v, 0.f);
          outh[(size_t)row * FDIM + col] = (_Float16)v;
          s += v; q += v * v;
        }
      }
    }
    // reduce over quad lanes (same col at lane ^16, ^32), then one atomic per col
    s += __shfl_xor(s, 16); q += __shfl_xor(q, 16);
    s += __shfl_xor(s, 32); q += __shfl_xor(q, 32);
    if (quad == 0) {
      atomicAdd(&ssum[col], s);
      atomicAdd(&ssq[col], q);
    }
  }
}

// ---------------- BN coeffs ----------------

// layer-1 coeffs + r2[n] = sum_k c1[k] * W2[k][n]  (c1 additive term folded into gemm2)
__global__ void coeffs1_kernel(const float* __restrict__ sum, const float* __restrict__ sq,
                               const float* __restrict__ gamma, const float* __restrict__ beta,
                               const float* __restrict__ W2, float* __restrict__ a,
                               float* __restrict__ r2, int N) {
  __shared__ float cc[FDIM];
  int t = threadIdx.x;  // 128
  float invn = 1.f / (float)N;
  float mean = sum[t] * invn;
  float var = sq[t] * invn - mean * mean;
  float rs = rsqrtf(var + 1e-5f);
  float av = gamma[t] * rs;
  a[t] = av;
  cc[t] = beta[t] - mean * av;
  __syncthreads();
  float acc = 0.f;
  for (int k = 0; k < FDIM; k++) acc += cc[k] * W2[k * FDIM + t];
  r2[t] = acc;
}

__global__ void coeffs_kernel(const float* __restrict__ sum, const float* __restrict__ sq,
                              const float* __restrict__ gamma, const float* __restrict__ beta,
                              float* __restrict__ a, float* __restrict__ c, int N) {
  int t = threadIdx.x;
  if (t < FDIM) {
    float invn = 1.f / (float)N;
    float mean = sum[t] * invn;
    float var = sq[t] * invn - mean * mean;
    float rs = rsqrtf(var + 1e-5f);
    float av = gamma[t] * rs;
    a[t] = av;
    c[t] = beta[t] - mean * av;
  }
}

// BN2: read fp16 h2, write fp32 out
__global__ void apply_h_kernel(const uint2* __restrict__ h4, const float* __restrict__ a,
                               const float* __restrict__ c, float4* __restrict__ out, int n4) {
  int i = blockIdx.x * blockDim.x + threadIdx.x;
  if (i < n4) {
    uint2 u = h4[i];
    float2 v0 = up2(u.x), v1 = up2(u.y);
    int c4 = i & 31;
    float4 av = ((const float4*)a)[c4];
    float4 cv = ((const float4*)c)[c4];
    float4 o;
    o.x = av.x * v0.x + cv.x;
    o.y = av.y * v0.y + cv.y;
    o.z = av.z * v1.x + cv.z;
    o.w = av.w * v1.y + cv.w;
    out[i] = o;
  }
}

// ---------------- launch ----------------

extern "C" void kernel_launch(void* const* d_in, const int* in_sizes, int n_in,
                              void* d_out, int out_size, void* d_ws, size_t ws_size,
                              hipStream_t stream) {
  const float* x   = (const float*)d_in[0];
  const int*   ei  = (const int*)d_in[1];
  const float* W1  = (const float*)d_in[2];
  const float* b1  = (const float*)d_in[3];
  const float* W2  = (const float*)d_in[4];
  const float* b2  = (const float*)d_in[5];
  const float* g1  = (const float*)d_in[6];
  const float* be1 = (const float*)d_in[7];
  const float* g2  = (const float*)d_in[8];
  const float* be2 = (const float*)d_in[9];
  float* out = (float*)d_out;

  const int N = in_sizes[0] / FDIM;
  const int E = in_sizes[1] / 2;
  const int* src = ei;
  const int* dst = ei + E;

  auto align256 = [](char*& q) { q = (char*)(((uintptr_t)q + 255) & ~(uintptr_t)255); };

  char* p = (char*)d_ws;
  int* deg = (int*)p;        p += (size_t)N * 4;
  float* stats = (float*)p;  p += 1280 * 4;   // s1 q1 s2 q2 a1 r2 a2 c2 (+pad)
  align256(p);
  int* row_start = (int*)p;  p += (size_t)N * 4; align256(p);
  int* fill_pos = (int*)p;   p += (size_t)N * 4; align256(p);
  int* csums = (int*)p;      p += 256 * 4;
  int* coffs = (int*)p;      p += 256 * 4; align256(p);
  int* ssrc = (int*)p;       p += (size_t)E * 4; align256(p);
  _Float16* xh  = (_Float16*)p; p += (size_t)N * FDIM * 2; align256(p);
  _Float16* tmp = (_Float16*)p; p += (size_t)N * FDIM * 2; align256(p);
  _Float16* h1  = (_Float16*)p; p += (size_t)N * FDIM * 2; align256(p);
  _Float16* Wf1 = (_Float16*)p; p += FDIM * FDIM * 2;
  _Float16* Wf2 = (_Float16*)p; p += FDIM * FDIM * 2;

  float* s1 = stats + 0,   *q1 = stats + 128;
  float* s2 = stats + 256, *q2 = stats + 384;
  float* a1 = stats + 512, *r2 = stats + 640;
  float* a2 = stats + 768, *c2 = stats + 896;

  const int nchunk = (N + 1023) / 1024;
  const int ntiles = (N + 63) / 64;
  const int step = (N + NGRP - 1) / NGRP;

  // CSR build + conversions
  int zn = N + 1280;  // deg + stats region (contiguous)
  zero_kernel<<<(zn + 255) / 256, 256, 0, stream>>>(deg, zn);
  hist_part_kernel<<<NGRP * 128, 256, 0, stream>>>(dst, deg, E, step);
  cvt_f2h_kernel<<<(N * 32 + 255) / 256, 256, 0, stream>>>(x, xh, N * 32);
  prepw_kernel<<<64, 256, 0, stream>>>(W1, Wf1);
  prepw_kernel<<<64, 256, 0, stream>>>(W2, Wf2);
  scan1_kernel<<<nchunk, 256, 0, stream>>>(deg, csums, N);
  scan2_kernel<<<1, 256, 0, stream>>>(csums, coffs, nchunk);
  scan3_kernel<<<nchunk, 256, 0, stream>>>(deg, coffs, row_start, fill_pos, N);
  place_part_kernel<<<NGRP * 128, 256, 0, stream>>>(src, dst, fill_pos, ssrc, E, step);

  // layer 1
  agg_kernel<false><<<(N + 3) / 4, 256, 0, stream>>>((const unsigned*)xh, row_start, deg,
                                                     ssrc, nullptr, (unsigned*)tmp, N);
  gemm_kernel<false><<<ntiles, 256, 0, stream>>>(tmp, Wf1, b1, nullptr, nullptr, h1,
                                                 s1, q1, N);
  coeffs1_kernel<<<1, 128, 0, stream>>>(s1, q1, g1, be1, W2, a1, r2, N);

  // layer 2: agg scales by a1; c1-term enters gemm2 as (deg+1)*r2
  agg_kernel<true><<<(N + 3) / 4, 256, 0, stream>>>((const unsigned*)h1, row_start, deg,
                                                    ssrc, a1, (unsigned*)tmp, N);
  gemm_kernel<true><<<ntiles, 256, 0, stream>>>(tmp, Wf2, b2, r2, deg, h1, s2, q2, N);
  coeffs_kernel<<<1, 128, 0, stream>>>(s2, q2, g2, be2, a2, c2, N);

  // BN2: fp16 h2 -> fp32 out
  int n4 = N * 32;
  apply_h_kernel<<<(n4 + 255) / 256, 256, 0, stream>>>((const uint2*)h1, a2, c2,
                                                       (float4*)out, n4);
}